// Round 8
// baseline (8811.435 us; speedup 1.0000x reference)
//
#include <hip/hip_runtime.h>
#include <cstdint>
#include <cstddef>

// ---------------------------------------------------------------------------
// Problem constants (ARU recurrence): B=32, S=1024, H=1024, 3H=3072
// ---------------------------------------------------------------------------
#define HID   1024
#define BATCH 32
#define SEQ   1024
#define NROWS 32768   /* BATCH*SEQ */
#define G3    3072
#define NWORK 64      /* recurrence worker WGs; WG g owns h-cols [16g,16g+16) */
#define HSLOT 32768   /* elements per h ring slot = BATCH*HID */

typedef __attribute__((ext_vector_type(8))) short bf16x8_t;
typedef __attribute__((ext_vector_type(4))) float f32x4_t;

__device__ __forceinline__ unsigned short f2bf(float f) {
  unsigned u = __float_as_uint(f);
  u += 0x7FFFu + ((u >> 16) & 1u);       // round-to-nearest-even
  return (unsigned short)(u >> 16);
}
__device__ __forceinline__ float bf2f(unsigned short s) {
  return __uint_as_float(((unsigned)s) << 16);
}

// write-through device-coherent 16-bit store: visible at the device coherence
// point (IF$) — VERIFIED protocol (rounds 0/5/7 passing kernels).
__device__ __forceinline__ void store_short_wt(unsigned short* p, unsigned short v) {
  asm volatile("global_store_short %0, %1, off sc0 sc1"
               :: "v"(p), "v"((unsigned)v) : "memory");
}

// ---------------------------------------------------------------------------
// K0: transpose + cast  W (1024 x N) fp32  ->  WT (N x 1024) bf16
// ---------------------------------------------------------------------------
__global__ __launch_bounds__(256) void transpose_cast(const float* __restrict__ in,
                                                      unsigned short* __restrict__ out,
                                                      int N) {
  __shared__ float tile[32][33];
  int k0 = blockIdx.x * 32, n0 = blockIdx.y * 32;
  int tx = threadIdx.x, ty = threadIdx.y;   // (32,8)
#pragma unroll
  for (int i = 0; i < 4; ++i)
    tile[ty + 8 * i][tx] = in[(size_t)(k0 + ty + 8 * i) * N + n0 + tx];
  __syncthreads();
#pragma unroll
  for (int i = 0; i < 4; ++i)
    out[(size_t)(n0 + ty + 8 * i) * HID + k0 + tx] = f2bf(tile[tx][ty + 8 * i]);
}

// ---------------------------------------------------------------------------
// K1: e = bf16(embed[x])   (32768 x 1024)
// ---------------------------------------------------------------------------
__global__ __launch_bounds__(256) void gather_cast(const int* __restrict__ x,
                                                   const float* __restrict__ embed,
                                                   unsigned short* __restrict__ e) {
  int r = blockIdx.x;
  int t = threadIdx.x;
  int tok = x[r];
  const float4* src = (const float4*)(embed + (size_t)tok * HID);
  float4 v = src[t];
  ushort4 o;
  o.x = f2bf(v.x); o.y = f2bf(v.y); o.z = f2bf(v.z); o.w = f2bf(v.w);
  ((ushort4*)(e + (size_t)r * HID))[t] = o;
}

// ---------------------------------------------------------------------------
// K2: fused GEMM  C = e(32768x1024) @ B'(1024x4096)   [B' stored as (4096x1024)]
//     Output is REPACKED s-major for the recurrence's per-step locality:
//       row2 = s*32 + b   (s = m & 1023, b = m >> 10)
//     cols [0,3072): gate_x = C + bgx   (bf16, gx[row2*G3 + n])
//     cols [3072,4096): cand = tanh(C + bc) (bf16, cand[row2*HID + n-G3])
// ---------------------------------------------------------------------------
__global__ __launch_bounds__(256) void gemm_fused(const unsigned short* __restrict__ A,
                                                  const unsigned short* __restrict__ B,
                                                  const float* __restrict__ bgx,
                                                  const float* __restrict__ bc,
                                                  unsigned short* __restrict__ gx,
                                                  unsigned short* __restrict__ cand) {
  __shared__ unsigned short As[128 * 32];
  __shared__ unsigned short Bs[128 * 32];
  const int bm = blockIdx.x * 128, bn = blockIdx.y * 128;
  const int t = threadIdx.x;
  const int wave = t >> 6, lane = t & 63;
  const int q = lane >> 4, nidx = lane & 15;
  const int wm = (wave & 1) * 64, wn = (wave >> 1) * 64;
  const int sr = t >> 2;
  const int kofs = (t & 3) * 8;

  f32x4_t acc[4][4];
#pragma unroll
  for (int i = 0; i < 4; ++i)
#pragma unroll
    for (int j = 0; j < 4; ++j) acc[i][j] = (f32x4_t){0.f, 0.f, 0.f, 0.f};

#pragma unroll 1
  for (int kt = 0; kt < HID; kt += 32) {
    __syncthreads();
#pragma unroll
    for (int c = 0; c < 2; ++c) {
      int row = c * 64 + sr;
      *(uint4*)(&As[row * 32 + kofs]) = *(const uint4*)(&A[(size_t)(bm + row) * HID + kt + kofs]);
      *(uint4*)(&Bs[row * 32 + kofs]) = *(const uint4*)(&B[(size_t)(bn + row) * HID + kt + kofs]);
    }
    __syncthreads();
    bf16x8_t af[4], bfr[4];
#pragma unroll
    for (int i = 0; i < 4; ++i)
      af[i] = *(const bf16x8_t*)(&As[(wm + i * 16 + nidx) * 32 + q * 8]);
#pragma unroll
    for (int j = 0; j < 4; ++j)
      bfr[j] = *(const bf16x8_t*)(&Bs[(wn + j * 16 + nidx) * 32 + q * 8]);
#pragma unroll
    for (int i = 0; i < 4; ++i)
#pragma unroll
      for (int j = 0; j < 4; ++j)
        acc[i][j] = __builtin_amdgcn_mfma_f32_16x16x32_bf16(af[i], bfr[j], acc[i][j], 0, 0, 0);
  }

#pragma unroll
  for (int i = 0; i < 4; ++i) {
#pragma unroll
    for (int j = 0; j < 4; ++j) {
#pragma unroll
      for (int reg = 0; reg < 4; ++reg) {
        int m = bm + wm + i * 16 + q * 4 + reg;
        int s = m & (SEQ - 1), b = m >> 10;
        size_t row2 = (size_t)s * BATCH + b;
        int n = bn + wn + j * 16 + nidx;
        float v = acc[i][j][reg];
        if (n < G3) {
          gx[row2 * G3 + n] = f2bf(v + bgx[n]);
        } else {
          int nc = n - G3;
          cand[row2 * HID + nc] = f2bf(tanhf(v + bc[nc]));
        }
      }
    }
  }
}

// ---------------------------------------------------------------------------
// K3a: zero flags[64]  (ring slot 0 is never read: t=0 skips the matvec)
// ---------------------------------------------------------------------------
__global__ __launch_bounds__(64) void init_state(unsigned int* __restrict__ fx) {
  fx[threadIdx.x] = 0u;
}

// ---------------------------------------------------------------------------
// K3b: canary — diagnostic sentinel, overwritten by a successful recurrence.
// absmax ~1e6 => recurrence never ran; ~0.09 => ran but wrong data.
// ---------------------------------------------------------------------------
__global__ __launch_bounds__(64) void canary(float* __restrict__ out) {
  out[threadIdx.x] = 1.0e6f;
}

// ---------------------------------------------------------------------------
// K3: recurrence — 64 WGs x 128 threads, weights in LDS (structural
// residency; rounds 5/7 proved the register allocator rematerializes
// register-resident weights -> per-step L2 reload chain = 7-9 us/step).
//  - WG g owns h-cols [16g,16g+16); wave = batch half (rows mh..mh+16).
//  - Weights: 3 gates x 16 cols x K=1024 bf16 = 96 KB, staged ONCE into LDS
//    in MFMA-fragment order: frag(gate,kt) at (gate*32+kt)*1024 + n*64 + q*16.
//    Uniform 8 dwords/bank per wave read -> conflict-free ds_read_b128.
//  - Per step per wave: 32 ring A-loads (b128, vmcnt path) + 96 ds_reads
//    (lgkmcnt path) + 96 MFMAs (3 acc chains); gx/cand for t+1 prefetched
//    after the first A-load (counted-vmcnt keeps MFMA independent of them).
//  COHERENCE (rounds 0/5/7 VERIFIED protocol):
//   - h stores: global_store_short sc0 sc1 (write-through to IF$)
//   - flag store/poll: __hip_atomic relaxed AGENT (monotonic counters)
//   - h loads: PLAIN cached b128, first-touch after one agent-acquire fence
//   - spin guard: any residual race becomes a visible FAIL, not a hang
// ---------------------------------------------------------------------------
__global__ __launch_bounds__(128, 1) void recurrence(const unsigned short* __restrict__ gx,
                                                     const unsigned short* __restrict__ cand,
                                                     const unsigned short* __restrict__ WghT,
                                                     unsigned short* __restrict__ ring,
                                                     unsigned int* __restrict__ flags,
                                                     float* __restrict__ out) {
  const int g = blockIdx.x;            // owns h-cols [16g, 16g+16)
  const int tid = threadIdx.x;         // 0..127
  const int lane = tid & 63;
  const int wave = tid >> 6;           // batch half
  const int q = lane >> 4, n = lane & 15;
  const int mh = wave * 16;
  const int colh = 16 * g + n;         // this lane's h/gate column

  __shared__ unsigned short wlds[49152];   // 96 KB fragment-ordered weights

  // ONE agent-acquire fence: drop stale cached lines (ring aliases e; also
  // clears flag/ring leftovers from previous harness iterations).
  __builtin_amdgcn_fence(__ATOMIC_ACQUIRE, "agent");

  // ---- stage Wgh^T (48 rows x 2KB) into fragment-ordered LDS ----
  for (int it = tid; it < 1536; it += 128) {
    int row = it >> 5;                 // gate*16 + nn
    int kt  = it & 31;
    int gate = row >> 4, nn = row & 15;
    const uint4* src = (const uint4*)(WghT + (size_t)(gate * 1024 + 16 * g + nn) * HID + kt * 32);
    uint4* dst = (uint4*)((char*)wlds + (size_t)(gate * 32 + kt) * 1024 + nn * 64);
    dst[0] = src[0]; dst[1] = src[1]; dst[2] = src[2]; dst[3] = src[3];
  }
  __syncthreads();

  const char* wbase = (const char*)wlds + n * 64 + q * 16;   // per-lane frag base

  float h_own[4] = {0.f, 0.f, 0.f, 0.f};
  unsigned short pcur[16], pnext[16];  // [0..3]=rho gx, [4..7]=pi gx,
                                       // [8..11]=alpha gx, [12..15]=cand

  // prologue prefetch (t = 0); s-major layout: row2 = t*32 + batch_row
#pragma unroll
  for (int r = 0; r < 4; ++r) {
    const size_t rb = (size_t)(mh + q * 4 + r);
    pcur[r]      = gx[rb * G3 + colh];
    pcur[4 + r]  = gx[rb * G3 + 1024 + colh];
    pcur[8 + r]  = gx[rb * G3 + 2048 + colh];
    pcur[12 + r] = cand[rb * HID + colh];
  }

#pragma unroll 1
  for (int t = 0; t < SEQ; ++t) {
    // ---- poll: all 64 producers published h(t) (agent/IF$-coherent) ----
    if (t > 0) {
      const unsigned int* fp = flags + lane;
      unsigned fv;
      int guard = 0;
      do {
        fv = __hip_atomic_load(fp, __ATOMIC_RELAXED, __HIP_MEMORY_SCOPE_AGENT);
      } while (__any(fv < (unsigned)t) && ++guard < 8192);
      asm volatile("" ::: "memory");   // pin h loads after the poll
    }

    const int tp = (t + 1 < SEQ) ? t + 1 : t;

    // ---- preact = h(t) @ Wgh_slice (A: ring via vmcnt; B: LDS via lgkmcnt)
    f32x4_t aR = (f32x4_t){0.f, 0.f, 0.f, 0.f};
    f32x4_t aP = (f32x4_t){0.f, 0.f, 0.f, 0.f};
    f32x4_t aA = (f32x4_t){0.f, 0.f, 0.f, 0.f};
    if (t > 0) {
      const unsigned short* ha = ring + ((size_t)t << 15)
                               + (size_t)(mh + n) * HID + q * 8;
#pragma unroll
      for (int kt = 0; kt < 32; ++kt) {
        bf16x8_t av = *(const bf16x8_t*)(ha + kt * 32);
        if (kt == 0) {
          // next-step gx/cand prefetch issued AFTER the first A-load:
          // counted vmcnt keeps MFMA A-waits independent of these HBM
          // loads; the MFMA region + drain hides their latency.
#pragma unroll
          for (int r = 0; r < 4; ++r) {
            const size_t rb = ((size_t)tp * BATCH + mh + q * 4 + r);
            pnext[r]      = gx[rb * G3 + colh];
            pnext[4 + r]  = gx[rb * G3 + 1024 + colh];
            pnext[8 + r]  = gx[rb * G3 + 2048 + colh];
            pnext[12 + r] = cand[rb * HID + colh];
          }
        }
        bf16x8_t w0 = *(const bf16x8_t*)(wbase + (size_t)(0 * 32 + kt) * 1024);
        bf16x8_t w1 = *(const bf16x8_t*)(wbase + (size_t)(1 * 32 + kt) * 1024);
        bf16x8_t w2 = *(const bf16x8_t*)(wbase + (size_t)(2 * 32 + kt) * 1024);
        aR = __builtin_amdgcn_mfma_f32_16x16x32_bf16(av, w0, aR, 0, 0, 0);
        aP = __builtin_amdgcn_mfma_f32_16x16x32_bf16(av, w1, aP, 0, 0, 0);
        aA = __builtin_amdgcn_mfma_f32_16x16x32_bf16(av, w2, aA, 0, 0, 0);
      }
    } else {
      // t = 0: no h yet; just issue the t=1 prefetch
#pragma unroll
      for (int r = 0; r < 4; ++r) {
        const size_t rb = ((size_t)tp * BATCH + mh + q * 4 + r);
        pnext[r]      = gx[rb * G3 + colh];
        pnext[4 + r]  = gx[rb * G3 + 1024 + colh];
        pnext[8 + r]  = gx[rb * G3 + 2048 + colh];
        pnext[12 + r] = cand[rb * HID + colh];
      }
    }

    // ---- gates + carry. D layout: col = n, row(batch) = q*4+r.
    unsigned short* hn = ring + ((size_t)(t + 1) << 15);
#pragma unroll
    for (int r = 0; r < 4; ++r) {
      float rho = 1.f / (1.f + __expf(-(aR[r] + bf2f(pcur[r]))));
      float pi  = 1.f / (1.f + __expf(-(aP[r] + bf2f(pcur[4 + r]))));
      float al  = 1.f / (1.f + __expf(-(aA[r] + bf2f(pcur[8 + r]))));
      h_own[r] = rho * (pi * h_own[r] + al * bf2f(pcur[12 + r]));
      // write-through sc0 sc1: visible at IF$; 16-lane groups coalesce 32B
      store_short_wt(&hn[(size_t)(mh + q * 4 + r) * HID + colh], f2bf(h_own[r]));
    }
#pragma unroll
    for (int r = 0; r < 16; ++r) pcur[r] = pnext[r];

    // publish: drain own stores to fabric (also completes prefetches), WG
    // rendezvous, one agent-scope flag store (monotonic counter)
    asm volatile("s_waitcnt vmcnt(0)" ::: "memory");
    __syncthreads();
    if (tid == 0)
      __hip_atomic_store(&flags[g], (unsigned)(t + 1),
                         __ATOMIC_RELAXED, __HIP_MEMORY_SCOPE_AGENT);
  }

#pragma unroll
  for (int r = 0; r < 4; ++r)
    out[(size_t)(mh + q * 4 + r) * HID + colh] = h_own[r];
}

// ---------------------------------------------------------------------------
// launcher
// ---------------------------------------------------------------------------
extern "C" void kernel_launch(void* const* d_in, const int* in_sizes, int n_in,
                              void* d_out, int out_size, void* d_ws, size_t ws_size,
                              hipStream_t stream) {
  const int*   x     = (const int*)d_in[0];
  const float* embed = (const float*)d_in[1];
  const float* Wc    = (const float*)d_in[2];
  const float* bc    = (const float*)d_in[3];
  const float* Wgx   = (const float*)d_in[4];
  const float* bgx   = (const float*)d_in[5];
  const float* Wgh   = (const float*)d_in[6];
  float* out = (float*)d_out;

  char* base = (char*)d_ws;
  unsigned short* e    = (unsigned short*)(base);                       // 32768x1024 bf16 = 64 MiB
  unsigned short* Bp   = (unsigned short*)(base + 67108864);            // 4096x1024 bf16  = 8 MiB
  unsigned short* WghT = (unsigned short*)(base + 75497472);            // 3072x1024 bf16  = 6 MiB
  unsigned short* gxb  = (unsigned short*)(base + 81788928);            // 32768x3072 bf16 = 192 MiB (s-major)
  unsigned short* cnd  = (unsigned short*)(base + 283115520);           // 32768x1024 bf16 = 64 MiB (s-major)
  // h ring: slot t = h(t), write-once, 1025 x 64KB. Aliases e + head of Bp
  // (both dead after gemm). Slot 0 is never touched (t=0 skips the matvec).
  unsigned short* ring  = (unsigned short*)(base);
  unsigned int*   flags = (unsigned int*)(base + 350224384);            // 64 u32

  transpose_cast<<<dim3(32, 96), dim3(32, 8), 0, stream>>>(Wgx, Bp, G3);
  transpose_cast<<<dim3(32, 32), dim3(32, 8), 0, stream>>>(Wc, Bp + (size_t)G3 * HID, HID);
  transpose_cast<<<dim3(32, 96), dim3(32, 8), 0, stream>>>(Wgh, WghT, G3);

  gather_cast<<<dim3(NROWS), dim3(256), 0, stream>>>(x, embed, e);

  gemm_fused<<<dim3(256, 32), dim3(256), 0, stream>>>(e, Bp, bgx, bc, gxb, cnd);

  // zero flags AFTER gemm, before recurrence
  init_state<<<dim3(1), dim3(64), 0, stream>>>(flags);

  // diagnostic sentinel: overwritten by recurrence; survives iff it never runs
  canary<<<dim3(1), dim3(64), 0, stream>>>(out);

  // 64 WGs x 128 thr, 96KB LDS -> 1 WG/CU. Coop launch for co-residency;
  // fall back to plain launch (64 WGs trivially co-resident; spin guard
  // converts any pathology into a visible FAIL, never a hang).
  void* args[] = {(void*)&gxb, (void*)&cnd, (void*)&WghT, (void*)&ring,
                  (void*)&flags, (void*)&out};
  hipError_t cerr = hipLaunchCooperativeKernel((const void*)recurrence,
                                               dim3(NWORK), dim3(128), args, 0, stream);
  if (cerr != hipSuccess) {
    recurrence<<<dim3(NWORK), dim3(128), 0, stream>>>(gxb, cnd, WghT, ring, flags, out);
  }
}